// Round 9
// baseline (141.535 us; speedup 1.0000x reference)
//
#include <hip/hip_runtime.h>
#include <hip/hip_bf16.h>
#include <math.h>
#include <stdint.h>

// Problem: B=64, SQ=64, SD=512, H=128
#define BB 64
#define SQN 64
#define SDN 512
#define HH 128

typedef __attribute__((ext_vector_type(8))) short bf16x8;     // 8 bf16 = 4 VGPRs
typedef __attribute__((ext_vector_type(16))) float f32x16;    // 16 acc regs

__device__ __forceinline__ short f2bf(float f) {
  union { float f; unsigned u; } x; x.f = f;
  unsigned r = x.u + 0x7fffu + ((x.u >> 16) & 1u);   // RNE
  return (short)(r >> 16);
}

__device__ __forceinline__ void gl_lds16(const short* g, short* l) {
  __builtin_amdgcn_global_load_lds(
      (const __attribute__((address_space(1))) unsigned int*)g,
      (__attribute__((address_space(3))) unsigned int*)l, 16, 0, 0);
}

// ---- fused compact + fp32->bf16 convert (row-major d, r6 version) -----------
__global__ __launch_bounds__(256)
void convert_all(const float* __restrict__ q, const float* __restrict__ dp,
                 const float* __restrict__ dn,
                 const int* __restrict__ mp, const int* __restrict__ mn,
                 short* __restrict__ oq, short* __restrict__ od,
                 int* __restrict__ nvalid, int* __restrict__ counter) {
  const int D_BLOCKS = (2 * BB * SDN) / 8;   // 8192 (8 rows/block, 32 thr/row)
  if (blockIdx.x < D_BLOCKS) {
    const int bs = blockIdx.x >> 6;          // 64 blocks per (side*64+b)
    const int j0 = (blockIdx.x & 63) * 8;    // first compacted row of block
    const int side = bs >> 6, b = bs & 63;
    const int* mask = (side ? mn : mp) + b * SDN;

    __shared__ int s_perm[8];
    __shared__ int s_pad32;

    if (threadIdx.x < 64) {                  // wave 0: exclusive scan of mask
      const int ln = threadIdx.x;
      int mreg[8];
      #pragma unroll
      for (int it = 0; it < 8; ++it) mreg[it] = mask[it * 64 + ln];
      int run = 0;
      #pragma unroll
      for (int it = 0; it < 8; ++it) {
        unsigned long long bal = __ballot(mreg[it] != 0);
        int pos = run + __popcll(bal & ((1ull << ln) - 1ull));
        if (mreg[it]) {
          unsigned rel = (unsigned)(pos - j0);
          if (rel < 8u) s_perm[rel] = it * 64 + ln;
        }
        run += (int)__popcll(bal);
      }
      if (ln < 8 && j0 + ln >= run) s_perm[ln] = -1;   // zero-fill slots
      if (ln == 0) {
        s_pad32 = (run + 31) & ~31;
        if (j0 == 0) nvalid[bs] = run;       // one writer per bs
      }
    }
    __syncthreads();

    const int j = j0 + (threadIdx.x >> 5);
    if (j >= s_pad32) return;                // never read by maxsim
    const int l32 = threadIdx.x & 31;
    const int src_t = s_perm[threadIdx.x >> 5];
    const float* srcmat = side ? dn : dp;
    float4 v = make_float4(0.f, 0.f, 0.f, 0.f);
    if (src_t >= 0)
      v = ((const float4*)(srcmat + ((size_t)b * SDN + src_t) * HH))[l32];
    short4 o; o.x = f2bf(v.x); o.y = f2bf(v.y); o.z = f2bf(v.z); o.w = f2bf(v.w);
    *(short4*)&od[((size_t)bs * SDN + j) * HH + l32 * 4] = o;
  } else {
    if (blockIdx.x == D_BLOCKS && threadIdx.x == 0) *counter = 0;  // maxsim ticket
    int i = (blockIdx.x - D_BLOCKS) * 256 + threadIdx.x;  // float4 index, exact
    float4 v = ((const float4*)q)[i];
    short4 o; o.x = f2bf(v.x); o.y = f2bf(v.y); o.z = f2bf(v.z); o.w = f2bf(v.w);
    *(short4*)&oq[i * 4] = o;
  }
}

// maxsim — ROUND 9: per-wave-EXCLUSIVE staging = V3's self-paced pipeline,
// made correct.
//
// r8 POST-MORTEM: barrier-free direct-global regressed (71us, MfmaUtil 20%):
// removing barriers ALSO removed the deep in-flight load pipeline — direct
// VGPR fragments force a vmcnt drain before each tile's MFMA chain; load
// latency fully exposed. r7-V3's 29us = gl_lds + counted vmcnt + NO barrier.
//
// THIS KERNEL: block = 2 queries x 4 bs, 4 waves. Chunk = 128 rows; wave w
// exclusively owns rows [32w,32w+32): stages them into its PRIVATE ring-2
// LDS slot (8 gl_lds16) and is the only reader -> zero cross-wave staging
// deps -> ZERO barriers in the main loop. Self-pacing: issue stage(k+1),
// s_waitcnt vmcnt(8) (own k landed; k+1's 8 stay in flight), ds_read+MFMA.
// Each dfrag feeds 4 chains (2 queries x 2 s-halves): 8 chains/SIMD at
// 2 waves/SIMD; MFMA:ds_read = 4:1. WAR on ring slot (same wave, in order;
// compiler's lgkmcnt before MFMA use of k-1 data precedes stage(k+1) issue).
// Finalize per bs: 4-way cross-wave max via s_fin + 2 raw s_barriers
// (lgkmcnt(0) before, NO vmcnt -> prefetch crosses). 8 barriers/kernel.
//
// VGPR ~248 (qfrag 128 + dv 32 + acc 64) -> launch_bounds(256,2), 8 waves/
// CU; LDS 66KB -> 2 blocks/CU. Grid 1024 = 32 aslots x 32 bgroups, XCD-
// swizzled (4 bgroups/XCD: 2MB d-slice + q fits per-XCD L2).
// Bit-exact: kc-chain order per (a,s,t) verbatim; fmax exact any order;
// v0+v1 + 5-step xor tree + loss replica verbatim -> absmax 0.0.
// Handoff: sc1 relaxed agent atomics + per-wave vmcnt(0) before final
// barrier; NO __threadfence (r2: wbl2+inv cache nuke).
__global__ __launch_bounds__(256, 2)
void maxsim_kernel(const short* __restrict__ qb,
                   const short* __restrict__ dc,
                   const int* __restrict__ nvalid,
                   float* __restrict__ scores,
                   int* __restrict__ counter,
                   float* __restrict__ out) {
  const int lid   = blockIdx.x + 32 * blockIdx.y;  // 0..1023
  const int xcd   = lid & 7;
  const int slot  = lid >> 3;                       // 0..127 within XCD
  const int aslot = slot & 31;                      // block's query pair
  const int bs0   = (xcd + 8 * (slot >> 5)) * 4;    // bgroup*4

  __shared__ __align__(16) short d_lds[4][2][32 * 128];  // per-wave ring-2, 64KB
  __shared__ float s_fin[4 * 2 * 2 * 32];                // [w][q][half][l31]
  __shared__ int s_ticket;
  __shared__ float part[16];

  const int tid = threadIdx.x;       // 0..255
  const int ln  = tid & 63;
  const int w   = tid >> 6;          // 0..3: owns rows [32w, 32w+32) per chunk
  const int l31 = ln & 31;
  const int kh  = ln >> 5;

  int nvv[4], nch[4];
  #pragma unroll
  for (int i = 0; i < 4; ++i) {
    nvv[i] = nvalid[bs0 + i];        // block-uniform
    nch[i] = (nvv[i] + 127) >> 7;    // 128-row chunks
  }

  // ---- q for BOTH queries, both s-halves: n = half*32+l31, k = kc*16+kh*8 ----
  bf16x8 qf[2][2][8];                // [q][half][kc] = 128 VGPRs, persistent
  #pragma unroll
  for (int qi = 0; qi < 2; ++qi) {
    #pragma unroll
    for (int half = 0; half < 2; ++half) {
      const short* qrow = qb + ((size_t)(aslot * 2 + qi) * SQN + half * 32 + l31) * HH + kh * 8;
      #pragma unroll
      for (int kc = 0; kc < 8; ++kc)
        qf[qi][half][kc] = *(const bf16x8*)(qrow + kc * 16);
    }
  }

  // per-lane chunk-invariant offsets (shorts)
  int src_off[8];                    // global: row_rel*128 + (c0^ (row&15))*8
  {
    int r0 = ln >> 4, c0 = ln & 15;
    #pragma unroll
    for (int it = 0; it < 8; ++it) {
      int row_rel = it * 4 + r0;
      src_off[it] = row_rel * HH + (c0 ^ (row_rel & 15)) * 8;
    }
  }
  int rd_off[8];                     // lds: l31*128 + ((kc*2+kh)^(l31&15))*8
  #pragma unroll
  for (int kc = 0; kc < 8; ++kc)
    rd_off[kc] = l31 * HH + (((kc * 2 + kh) ^ (l31 & 15)) * 8);

  float rmax[2][2] = {{0.f, 0.f}, {0.f, 0.f}};   // [q][half]; true max >= 0

  // stage this wave's 32 rows of chunk (pbi,ptc) into ring slot rs
  auto STAGE = [&](int pbi, int ptc, int rs) {
    const short* dsrc = dc + (((size_t)(bs0 + pbi) * SDN) + ptc * 128 + w * 32) * HH;
    short* slotp = &d_lds[w][rs][0];
    #pragma unroll
    for (int it = 0; it < 8; ++it)
      gl_lds16(dsrc + src_off[it], slotp + it * 512);
  };

  // ---- prologue: stage flat chunk 0 ----
  int pbi = 0, ptc = 0;
  STAGE(pbi, ptc, 0);
  if (++ptc == nch[pbi]) { ptc = 0; ++pbi; }

  int cbi = 0, ctc = 0, ring = 0;
  for (;;) {
    const bool hn = (pbi < 4);
    if (hn) {
      STAGE(pbi, ptc, ring ^ 1);                 // k+1 issued
      if (++ptc == nch[pbi]) { ptc = 0; ++pbi; }
      asm volatile("s_waitcnt vmcnt(8)" ::: "memory");  // own k landed
    } else {
      asm volatile("s_waitcnt vmcnt(0)" ::: "memory");  // drain final chunk
    }

    // ---- compute chunk (cbi,ctc): wave's 32 rows, 2 queries x 2 halves ----
    const int rows = nvv[cbi] - (ctc << 7);      // rows in this chunk (1..128)
    if (w * 32 < rows) {                         // wave-uniform predicate
      const short* slotp = &d_lds[w][ring][0];
      bf16x8 dv[8];
      #pragma unroll
      for (int kc = 0; kc < 8; ++kc)
        dv[kc] = *(const bf16x8*)(slotp + rd_off[kc]);
      f32x16 a00 = {0,0,0,0,0,0,0,0,0,0,0,0,0,0,0,0};
      f32x16 a01 = {0,0,0,0,0,0,0,0,0,0,0,0,0,0,0,0};
      f32x16 a10 = {0,0,0,0,0,0,0,0,0,0,0,0,0,0,0,0};
      f32x16 a11 = {0,0,0,0,0,0,0,0,0,0,0,0,0,0,0,0};
      #pragma unroll
      for (int kc = 0; kc < 8; ++kc) {           // chained kc order = original
        a00 = __builtin_amdgcn_mfma_f32_32x32x16_bf16(dv[kc], qf[0][0][kc], a00, 0, 0, 0);
        a01 = __builtin_amdgcn_mfma_f32_32x32x16_bf16(dv[kc], qf[0][1][kc], a01, 0, 0, 0);
        a10 = __builtin_amdgcn_mfma_f32_32x32x16_bf16(dv[kc], qf[1][0][kc], a10, 0, 0, 0);
        a11 = __builtin_amdgcn_mfma_f32_32x32x16_bf16(dv[kc], qf[1][1][kc], a11, 0, 0, 0);
      }
      float m00 = a00[0], m01 = a01[0], m10 = a10[0], m11 = a11[0];
      #pragma unroll
      for (int r = 1; r < 16; ++r) {
        m00 = fmaxf(m00, a00[r]);  m01 = fmaxf(m01, a01[r]);
        m10 = fmaxf(m10, a10[r]);  m11 = fmaxf(m11, a11[r]);
      }
      rmax[0][0] = fmaxf(rmax[0][0], m00);
      rmax[0][1] = fmaxf(rmax[0][1], m01);
      rmax[1][0] = fmaxf(rmax[1][0], m10);
      rmax[1][1] = fmaxf(rmax[1][1], m11);
    }

    // ---- advance compute; finalize bs when it wraps (block-uniform) ----
    const int obi = cbi;
    if (++ctc == nch[cbi]) {
      ctc = 0; ++cbi;
      // cross-kh merge (lanes l, l+32 hold same rows, different k-groups)
      float v[2][2];
      #pragma unroll
      for (int qi = 0; qi < 2; ++qi)
        #pragma unroll
        for (int half = 0; half < 2; ++half)
          v[qi][half] = fmaxf(rmax[qi][half], __shfl_xor(rmax[qi][half], 32));
      if (kh == 0) {                       // lanes 0..31 publish
        #pragma unroll
        for (int qi = 0; qi < 2; ++qi)
          #pragma unroll
          for (int half = 0; half < 2; ++half)
            s_fin[((w * 2 + qi) * 2 + half) * 32 + l31] = v[qi][half];
      }
      asm volatile("s_waitcnt lgkmcnt(0)" ::: "memory");
      __builtin_amdgcn_s_barrier();        // raw: prefetch stays in flight
      if (w < 2) {                         // wave w finalizes query qi = w
        float m0 = s_fin[((0 * 2 + w) * 2 + 0) * 32 + l31];
        float m1 = s_fin[((0 * 2 + w) * 2 + 1) * 32 + l31];
        #pragma unroll
        for (int ww = 1; ww < 4; ++ww) {
          m0 = fmaxf(m0, s_fin[((ww * 2 + w) * 2 + 0) * 32 + l31]);
          m1 = fmaxf(m1, s_fin[((ww * 2 + w) * 2 + 1) * 32 + l31]);
        }
        float s = m0 + m1;                 // original v0+v1 operand order
        s += __shfl_xor(s, 1);  s += __shfl_xor(s, 2);  s += __shfl_xor(s, 4);
        s += __shfl_xor(s, 8);  s += __shfl_xor(s, 16);
        if (ln == 0)
          __hip_atomic_store(&scores[(size_t)(aslot * 2 + w) * (2 * BB) + bs0 + obi],
                             s, __ATOMIC_RELAXED, __HIP_MEMORY_SCOPE_AGENT);
      }
      __builtin_amdgcn_s_barrier();        // WAR: s_fin reused next bs
      rmax[0][0] = 0.f; rmax[0][1] = 0.f; rmax[1][0] = 0.f; rmax[1][1] = 0.f;
    }

    if (cbi == 4) break;
    ring ^= 1;
  }

  // ---- fused loss: last block to finish computes it (cache-op-free) ----
  asm volatile("s_waitcnt vmcnt(0)" ::: "memory");  // own sc1 stores at LLC
  __syncthreads();                                  // all waves drained
  if (tid == 0)
    s_ticket = __hip_atomic_fetch_add(counter, 1,
                                      __ATOMIC_RELAXED, __HIP_MEMORY_SCOPE_AGENT);
  __syncthreads();
  if (s_ticket != 1023) return;

  // Bitwise-identical replica of the original 16-partial loss reduction:
  // part[vp] (vp=0..15) covers rows 4vp..4vp+3; waves 0..3 compute vp=4w..4w+3;
  // wave 0 then runs the exact 16-lane xor tree. sc1 loads read the LLC.
  {
    #pragma unroll
    for (int q8 = 0; q8 < 4; ++q8) {
      int vp = w * 4 + q8;
      float acc = 0.f;
      #pragma unroll
      for (int i = 0; i < 4; ++i) {
        int r = vp * 4 + i;
        float v0 = __hip_atomic_load(&scores[r * 128 + ln],
                                     __ATOMIC_RELAXED, __HIP_MEMORY_SCOPE_AGENT);
        float v1 = __hip_atomic_load(&scores[r * 128 + 64 + ln],
                                     __ATOMIC_RELAXED, __HIP_MEMORY_SCOPE_AGENT);
        float mx = fmaxf(v0, v1);
        #pragma unroll
        for (int off = 32; off >= 1; off >>= 1) mx = fmaxf(mx, __shfl_xor(mx, off));
        float e = __expf(v0 - mx) + __expf(v1 - mx);
        #pragma unroll
        for (int off = 32; off >= 1; off >>= 1) e += __shfl_xor(e, off);
        float lse = mx + __logf(e);
        float diag = __shfl(v0, r);   // r < 64, diagonal lives in v0 at lane r
        acc += lse - diag;
      }
      if (ln == 0) part[vp] = acc;
    }
  }
  __syncthreads();
  if (w == 0) {
    float v = (ln < 16) ? part[ln] : 0.f;
    #pragma unroll
    for (int off = 8; off >= 1; off >>= 1) v += __shfl_xor(v, off);
    if (ln == 0) out[0] = v * (1.0f / 64.0f);
  }
}

extern "C" void kernel_launch(void* const* d_in, const int* in_sizes, int n_in,
                              void* d_out, int out_size, void* d_ws, size_t ws_size,
                              hipStream_t stream) {
  const float* q        = (const float*)d_in[0];
  const float* d_pos    = (const float*)d_in[1];
  const float* d_neg    = (const float*)d_in[2];
  const int*   mask_pos = (const int*)d_in[3];
  const int*   mask_neg = (const int*)d_in[4];

  // ws layout: q_bf 1 MB | d_c 16 MB | nvalid | scores | counter
  short* q_bf = (short*)d_ws;                                  // 524288 shorts
  short* d_c  = q_bf + (size_t)BB * SQN * HH;                  // 8388608 shorts
  int*   nvalid  = (int*)(d_c + (size_t)2 * BB * SDN * HH);    // 128 ints
  float* scores  = (float*)(nvalid + 128);                     // 8192 floats
  int*   counter = (int*)(scores + 64 * 128);                  // 1 int

  const int D_BLOCKS = (2 * BB * SDN) / 8;          // 8192
  const int Q_BLOCKS = (BB * SQN * HH / 4) / 256;   // 512
  convert_all<<<D_BLOCKS + Q_BLOCKS, 256, 0, stream>>>(
      q, d_pos, d_neg, mask_pos, mask_neg, q_bf, d_c, nvalid, counter);

  dim3 grid(32, 32);   // 1024 blocks = 32 aslots x 32 bgroups (XCD-swizzled)
  maxsim_kernel<<<grid, 256, 0, stream>>>(q_bf, d_c, nvalid, scores,
                                          counter, (float*)d_out);
}